// Round 4
// baseline (203.661 us; speedup 1.0000x reference)
//
#include <hip/hip_runtime.h>

// Problem constants (from reference setup_inputs):
// b=16, c=64, l=8, h=56, w=56  ->  cl = 512, n = 56*56 = 3136
#define BATCH 16
#define CL    512
#define NSP   3136
#define N4    (NSP / 4)            // 784 float4 per (b,c) row
#define CHUNK 8                    // i4 positions per pass-1 block
#define NCHUNK (N4 / CHUNK)        // 98 (exact: 98*8 = 784)
#define GROUPS 32                  // channel groups per pass-1 block
#define CPG   (CL / GROUPS)        // 16 channels per group

// Native vector type usable with __builtin_nontemporal_store
typedef float nfloat4 __attribute__((ext_vector_type(4)));

// ---------------------------------------------------------------------------
// Pass 1: g[b,i] = sum_c x[b,c,i]*g_w[c]  (final, no partials)
//         t_part[b,chunk] = sum_{i in chunk} sum_c x[b,c,i]*theta_w[c]
// Block: 256 threads = 8 i4-lanes x 32 channel-groups (covers all 512 ch).
// Grid:  (BATCH, NCHUNK) = (16, 98) = 1568 blocks -> 6-7 blocks/CU
// (vs 400 blocks before: critical-path CU drops from 512 KB to ~448 KB).
// ---------------------------------------------------------------------------
__global__ __launch_bounds__(256) void sa_pass1(
    const float* __restrict__ x,        // [BATCH, CL, NSP]
    const float* __restrict__ theta_w,  // [CL]
    const float* __restrict__ g_w,      // [CL]
    float* __restrict__ g_out,          // [BATCH, NSP]     (ws)
    float* __restrict__ t_part)         // [BATCH, NCHUNK]  (ws)
{
    const int b     = blockIdx.x;
    const int chunk = blockIdx.y;
    const int tid   = threadIdx.x;
    const int tx    = tid & (CHUNK - 1);   // i4 lane 0..7
    const int gq    = tid >> 3;            // channel group 0..31
    const int i4    = chunk * CHUNK + tx;  // always < N4 (exact tiling)

    const float4* xb = (const float4*)x + (size_t)b * CL * N4;

    float4 gv = make_float4(0.f, 0.f, 0.f, 0.f);
    float4 tv = make_float4(0.f, 0.f, 0.f, 0.f);
    {
        const int c0 = gq * CPG;
        #pragma unroll
        for (int c = c0; c < c0 + CPG; ++c) {
            float4 xv = xb[(size_t)c * N4 + i4];   // 8 lanes x 16B = 128B seg
            float gw = g_w[c];
            float tw = theta_w[c];
            gv.x += xv.x * gw; gv.y += xv.y * gw;
            gv.z += xv.z * gw; gv.w += xv.w * gw;
            tv.x += xv.x * tw; tv.y += xv.y * tw;
            tv.z += xv.z * tw; tv.w += xv.w * tw;
        }
    }

    __shared__ float4 sg[GROUPS][CHUNK];
    __shared__ float4 st[GROUPS][CHUNK];
    sg[gq][tx] = gv;
    st[gq][tx] = tv;
    __syncthreads();

    // Stage 1: 64 threads fold 32 groups -> 8 (each sums groups k, k+8, k+16, k+24)
    if (tid < 64) {
        const int lx = tid & (CHUNK - 1);
        const int k  = tid >> 3;           // 0..7
        float4 G = sg[k][lx];
        float4 T = st[k][lx];
        #pragma unroll
        for (int s = 8; s < GROUPS; s += 8) {
            float4 a  = sg[k + s][lx];
            float4 t2 = st[k + s][lx];
            G.x += a.x;  G.y += a.y;  G.z += a.z;  G.w += a.w;
            T.x += t2.x; T.y += t2.y; T.z += t2.z; T.w += t2.w;
        }
        sg[k][lx] = G;
        st[k][lx] = T;
    }
    __syncthreads();

    // Stage 2: 8 threads fold 8 -> 1, write g, reduce t across the 8 lanes.
    if (tid < CHUNK) {
        float4 G = sg[0][tid];
        float4 T = st[0][tid];
        #pragma unroll
        for (int k = 1; k < 8; ++k) {
            float4 a  = sg[k][tid];
            float4 t2 = st[k][tid];
            G.x += a.x;  G.y += a.y;  G.z += a.z;  G.w += a.w;
            T.x += t2.x; T.y += t2.y; T.z += t2.z; T.w += t2.w;
        }
        ((float4*)g_out)[(size_t)b * N4 + chunk * CHUNK + tid] = G;

        float s = T.x + T.y + T.z + T.w;
        #pragma unroll
        for (int off = 4; off > 0; off >>= 1)
            s += __shfl_down(s, off, 8);
        if (tid == 0)
            t_part[b * NCHUNK + chunk] = s;
    }
}

// ---------------------------------------------------------------------------
// Pass 2: out[b,c,i] = x[b,c,i] + (m[b]/NSP)*g[b,i]*h_w[c] + h_b[c]
// Block covers 1024 consecutive float4 (4 per thread); 401408 float4 per
// batch is divisible by 1024 (392 blocks/batch), so one batch per block.
// Grid: 6422528/1024 = 6272 blocks.
// ---------------------------------------------------------------------------
#define P2_F4_PER_BLOCK 1024
__global__ __launch_bounds__(256) void sa_pass2(
    const float* __restrict__ x,
    const float* __restrict__ g_arr,   // [BATCH, NSP]
    const float* __restrict__ t_part,  // [BATCH, NCHUNK]
    const float* __restrict__ h_w,     // [CL]
    const float* __restrict__ h_b,     // [CL]
    float* __restrict__ out)
{
    const int blk = blockIdx.x;
    const int b   = blk / ((CL * N4) / P2_F4_PER_BLOCK);   // 392 blocks/batch

    // Reduce the 98 t-partials for this batch -> m (once per block).
    __shared__ float red[2];
    __shared__ float sm;
    const int tid = threadIdx.x;
    if (tid < 128) {
        float v = (tid < NCHUNK) ? t_part[b * NCHUNK + tid] : 0.f;
        #pragma unroll
        for (int off = 32; off > 0; off >>= 1)
            v += __shfl_down(v, off, 64);
        if ((tid & 63) == 0)
            red[tid >> 6] = v;
    }
    __syncthreads();
    if (tid == 0)
        sm = (red[0] + red[1]) * (1.0f / (float)NSP);
    __syncthreads();
    const float m = sm;

    const size_t base = (size_t)blk * P2_F4_PER_BLOCK + tid;
    #pragma unroll
    for (int r = 0; r < P2_F4_PER_BLOCK / 256; ++r) {
        const size_t f = base + (size_t)r * 256;     // float4 index
        const int i4 = (int)(f % N4);
        const int bc = (int)(f / N4);
        const int c  = bc & (CL - 1);

        float4 xv = ((const float4*)x)[f];
        float4 gv = ((const float4*)g_arr)[(size_t)b * N4 + i4];
        const float hw = h_w[c];
        const float hb = h_b[c];
        const float mh = m * hw;

        nfloat4 o;
        o.x = xv.x + mh * gv.x + hb;
        o.y = xv.y + mh * gv.y + hb;
        o.z = xv.z + mh * gv.z + hb;
        o.w = xv.w + mh * gv.w + hb;
        // Nontemporal: out is never re-read; keep x resident in L2/L3.
        __builtin_nontemporal_store(o, (nfloat4*)out + f);
    }
}

extern "C" void kernel_launch(void* const* d_in, const int* in_sizes, int n_in,
                              void* d_out, int out_size, void* d_ws, size_t ws_size,
                              hipStream_t stream)
{
    const float* x       = (const float*)d_in[0];
    const float* theta_w = (const float*)d_in[1];
    const float* g_w     = (const float*)d_in[2];
    const float* h_w     = (const float*)d_in[3];
    const float* h_b     = (const float*)d_in[4];
    float* out = (float*)d_out;

    // Workspace layout (fully written by pass1 before pass2 reads it):
    //   [0, BATCH*NCHUNK floats)            : t_part (16*98 = 1568 floats)
    //   [8192 B, 8192 B + BATCH*NSP floats) : g
    float* t_ws = (float*)d_ws;
    float* g_ws = (float*)((char*)d_ws + 8192);

    dim3 grid1(BATCH, NCHUNK);   // (16, 98)
    sa_pass1<<<grid1, 256, 0, stream>>>(x, theta_w, g_w, g_ws, t_ws);

    const int total4 = BATCH * CL * N4;
    sa_pass2<<<total4 / P2_F4_PER_BLOCK, 256, 0, stream>>>(x, g_ws, t_ws, h_w, h_b, out);
}